// Round 1
// baseline (774.363 us; speedup 1.0000x reference)
//
#include <hip/hip_runtime.h>
#include <hip/hip_bf16.h>
#include <math.h>

#define BATCH 8192
#define LDT 512  // top_in row stride (506 used, padded)

// ---------------------------------------------------------------------------
// Kernel 1: fused bottom MLP  13 -> 512 -> 256 -> 128 (ReLU each)
// 8 rows per block, 256 threads. Writes result into top_in[:, 0:128].
// ---------------------------------------------------------------------------
__global__ __launch_bounds__(256) void bottom_mlp_kernel(
    const float* __restrict__ dense,   // (B,13)
    const float* __restrict__ W0, const float* __restrict__ b0,  // (13,512),(512)
    const float* __restrict__ W1, const float* __restrict__ b1,  // (512,256),(256)
    const float* __restrict__ W2, const float* __restrict__ b2,  // (256,128),(128)
    float* __restrict__ top_in)        // (B, LDT)
{
    __shared__ float xs[8][16];
    __shared__ float h1s[8][512];
    __shared__ float h2s[8][260];   // padded stride

    const int t = threadIdx.x;
    const int row0 = blockIdx.x * 8;

    if (t < 8 * 13) {
        int r = t / 13, k = t % 13;
        xs[r][k] = dense[(size_t)(row0 + r) * 13 + k];
    }
    __syncthreads();

    // ---- layer 1: 512 outputs; thread does j=t and j=t+256 ----
    #pragma unroll
    for (int jj = 0; jj < 2; ++jj) {
        const int j = t + jj * 256;
        float acc[8];
        const float bj = b0[j];
        #pragma unroll
        for (int r = 0; r < 8; ++r) acc[r] = bj;
        #pragma unroll
        for (int k = 0; k < 13; ++k) {
            float w = W0[k * 512 + j];
            #pragma unroll
            for (int r = 0; r < 8; ++r) acc[r] += xs[r][k] * w;
        }
        #pragma unroll
        for (int r = 0; r < 8; ++r) h1s[r][j] = fmaxf(acc[r], 0.f);
    }
    __syncthreads();

    // ---- layer 2: 256 outputs; thread does j=t ----
    {
        const int j = t;
        float acc[8];
        const float bj = b1[j];
        #pragma unroll
        for (int r = 0; r < 8; ++r) acc[r] = bj;
        for (int k = 0; k < 512; k += 4) {
            float w0 = W1[(k + 0) * 256 + j];
            float w1 = W1[(k + 1) * 256 + j];
            float w2 = W1[(k + 2) * 256 + j];
            float w3 = W1[(k + 3) * 256 + j];
            #pragma unroll
            for (int r = 0; r < 8; ++r) {
                float4 h = *reinterpret_cast<const float4*>(&h1s[r][k]);
                acc[r] += h.x * w0 + h.y * w1 + h.z * w2 + h.w * w3;
            }
        }
        #pragma unroll
        for (int r = 0; r < 8; ++r) h2s[r][j] = fmaxf(acc[r], 0.f);
    }
    __syncthreads();

    // ---- layer 3: 128 outputs; thread t: j = t&127, rows (t>>7)*4 .. +3 ----
    {
        const int j = t & 127;
        const int r0 = (t >> 7) * 4;
        float acc[4];
        const float bj = b2[j];
        #pragma unroll
        for (int q = 0; q < 4; ++q) acc[q] = bj;
        for (int k = 0; k < 256; k += 4) {
            float w0 = W2[(k + 0) * 128 + j];
            float w1 = W2[(k + 1) * 128 + j];
            float w2 = W2[(k + 2) * 128 + j];
            float w3 = W2[(k + 3) * 128 + j];
            #pragma unroll
            for (int q = 0; q < 4; ++q) {
                float4 h = *reinterpret_cast<const float4*>(&h2s[r0 + q][k]);
                acc[q] += h.x * w0 + h.y * w1 + h.z * w2 + h.w * w3;
            }
        }
        #pragma unroll
        for (int q = 0; q < 4; ++q)
            top_in[(size_t)(row0 + r0 + q) * LDT + j] = fmaxf(acc[q], 0.f);
    }
}

// ---------------------------------------------------------------------------
// Kernel 2: embedding gather + pairwise interaction.
// One row per block, 256 threads. feats[0]=bot_out (from top_in[:,0:128]),
// feats[1..26]=embedding rows. Writes 378 upper-tri dots to top_in[:,128:506].
// ---------------------------------------------------------------------------
__global__ __launch_bounds__(256) void interact_kernel(
    const int* __restrict__ cat,       // (B,26)
    const float* __restrict__ table,   // (2.6M,128)
    float* __restrict__ top_in)        // (B, LDT)
{
    __shared__ float fs[27][132];      // padded to break bank conflicts
    __shared__ int idx[26];

    const int t = threadIdx.x;
    const int row = blockIdx.x;

    if (t < 26) idx[t] = cat[(size_t)row * 26 + t] + t * 100000;
    __syncthreads();

    // load 27 * 128 floats = 864 float4
    for (int q = t; q < 27 * 32; q += 256) {
        const int i  = q >> 5;
        const int c4 = q & 31;
        const float* src = (i == 0) ? (top_in + (size_t)row * LDT)
                                    : (table + (size_t)idx[i - 1] * 128);
        float4 v = reinterpret_cast<const float4*>(src)[c4];
        fs[i][c4 * 4 + 0] = v.x;
        fs[i][c4 * 4 + 1] = v.y;
        fs[i][c4 * 4 + 2] = v.z;
        fs[i][c4 * 4 + 3] = v.w;
    }
    __syncthreads();

    // 378 pairs (i<=j), row-major triu order
    for (int p = t; p < 378; p += 256) {
        int i = 0, rem = p;
        while (rem >= 27 - i) { rem -= 27 - i; ++i; }
        const int j = i + rem;
        float s = 0.f;
        for (int k = 0; k < 128; k += 4) {
            float4 a = *reinterpret_cast<const float4*>(&fs[i][k]);
            float4 b = *reinterpret_cast<const float4*>(&fs[j][k]);
            s += a.x * b.x + a.y * b.y + a.z * b.z + a.w * b.w;
        }
        top_in[(size_t)row * LDT + 128 + p] = s;
    }
}

// ---------------------------------------------------------------------------
// Kernel 3: generic fp32 GEMM  C = act(A*B + bias), 64x64 tile, BK=16,
// 4x4 microtile per thread (256 threads). A:(M,lda) B:(K,ldb) row-major.
// ---------------------------------------------------------------------------
__global__ __launch_bounds__(256) void gemm_bias_act_kernel(
    const float* __restrict__ A, int lda,
    const float* __restrict__ B, int ldb,
    const float* __restrict__ bias,
    float* __restrict__ C, int ldc,
    int K, int relu)
{
    __shared__ float As[16][68];
    __shared__ float Bs[16][64];

    const int t = threadIdx.x;
    const int row0 = blockIdx.x * 64;
    const int col0 = blockIdx.y * 64;
    const int ty = t >> 4, tx = t & 15;
    const int m0 = ty * 4, n0 = tx * 4;

    // staging roles
    const int am  = t >> 2;            // 0..63 row within A tile
    const int akq = (t & 3) * 4;       // 0,4,8,12: k sub-block
    const int bk  = t >> 4;            // 0..15: k row of B tile
    const int bn  = (t & 15) * 4;      // col within B tile

    const float* Arow  = A + (size_t)(row0 + am) * lda;
    const float* Bbase = B + col0 + bn;

    float acc[4][4] = {};

    for (int k0 = 0; k0 < K; k0 += 16) {
        // stage A (guarded, zero-fill past K)
        #pragma unroll
        for (int i = 0; i < 4; ++i) {
            int kk = k0 + akq + i;
            As[akq + i][am] = (kk < K) ? Arow[kk] : 0.f;
        }
        // stage B (float4, guarded)
        {
            int kk = k0 + bk;
            float4 v = make_float4(0.f, 0.f, 0.f, 0.f);
            if (kk < K) v = *reinterpret_cast<const float4*>(Bbase + (size_t)kk * ldb);
            *reinterpret_cast<float4*>(&Bs[bk][bn]) = v;
        }
        __syncthreads();

        #pragma unroll
        for (int k = 0; k < 16; ++k) {
            float4 a = *reinterpret_cast<const float4*>(&As[k][m0]);
            float4 b = *reinterpret_cast<const float4*>(&Bs[k][n0]);
            acc[0][0] += a.x * b.x; acc[0][1] += a.x * b.y; acc[0][2] += a.x * b.z; acc[0][3] += a.x * b.w;
            acc[1][0] += a.y * b.x; acc[1][1] += a.y * b.y; acc[1][2] += a.y * b.z; acc[1][3] += a.y * b.w;
            acc[2][0] += a.z * b.x; acc[2][1] += a.z * b.y; acc[2][2] += a.z * b.z; acc[2][3] += a.z * b.w;
            acc[3][0] += a.w * b.x; acc[3][1] += a.w * b.y; acc[3][2] += a.w * b.z; acc[3][3] += a.w * b.w;
        }
        __syncthreads();
    }

    // epilogue: bias + activation, float4 stores
    const float bx = bias[col0 + n0 + 0];
    const float by = bias[col0 + n0 + 1];
    const float bz = bias[col0 + n0 + 2];
    const float bw = bias[col0 + n0 + 3];
    #pragma unroll
    for (int i = 0; i < 4; ++i) {
        float4 v;
        v.x = acc[i][0] + bx;
        v.y = acc[i][1] + by;
        v.z = acc[i][2] + bz;
        v.w = acc[i][3] + bw;
        if (relu) {
            v.x = fmaxf(v.x, 0.f); v.y = fmaxf(v.y, 0.f);
            v.z = fmaxf(v.z, 0.f); v.w = fmaxf(v.w, 0.f);
        }
        *reinterpret_cast<float4*>(C + (size_t)(row0 + m0 + i) * ldc + col0 + n0) = v;
    }
}

// ---------------------------------------------------------------------------
// Kernel 4: final layer 256 -> 1 + sigmoid. One wave (64 lanes) per row.
// ---------------------------------------------------------------------------
__global__ __launch_bounds__(256) void final_layer_kernel(
    const float* __restrict__ A,   // (B,256)
    const float* __restrict__ T4,  // (256,1)
    const float* __restrict__ tb4, // (1)
    float* __restrict__ out)       // (B)
{
    const int t = threadIdx.x;
    const int lane = t & 63;
    const int wave = t >> 6;
    const int row = blockIdx.x * 4 + wave;

    float4 a = reinterpret_cast<const float4*>(A + (size_t)row * 256)[lane];
    float4 w = reinterpret_cast<const float4*>(T4)[lane];
    float s = a.x * w.x + a.y * w.y + a.z * w.z + a.w * w.w;
    #pragma unroll
    for (int off = 32; off > 0; off >>= 1) s += __shfl_down(s, off, 64);
    if (lane == 0) out[row] = 1.f / (1.f + expf(-(s + tb4[0])));
}

// ---------------------------------------------------------------------------
extern "C" void kernel_launch(void* const* d_in, const int* in_sizes, int n_in,
                              void* d_out, int out_size, void* d_ws, size_t ws_size,
                              hipStream_t stream)
{
    const float* dense = (const float*)d_in[0];
    const int*   cat   = (const int*)d_in[1];
    const float* table = (const float*)d_in[2];
    const float* W0 = (const float*)d_in[3];
    const float* b0 = (const float*)d_in[4];
    const float* W1 = (const float*)d_in[5];
    const float* b1 = (const float*)d_in[6];
    const float* W2 = (const float*)d_in[7];
    const float* b2 = (const float*)d_in[8];
    const float* T0 = (const float*)d_in[9];
    const float* tb0 = (const float*)d_in[10];
    const float* T1 = (const float*)d_in[11];
    const float* tb1 = (const float*)d_in[12];
    const float* T2 = (const float*)d_in[13];
    const float* tb2 = (const float*)d_in[14];
    const float* T3 = (const float*)d_in[15];
    const float* tb3 = (const float*)d_in[16];
    const float* T4 = (const float*)d_in[17];
    const float* tb4 = (const float*)d_in[18];
    float* out = (float*)d_out;

    // workspace layout (floats)
    float* top_in = (float*)d_ws;                         // 8192 x 512   (16 MB)
    float* bufX = top_in + (size_t)BATCH * LDT;           // 8192 x 1024  (32 MB)
    float* bufY = bufX + (size_t)BATCH * 1024;            // 8192 x 1024  (32 MB)

    // 1) bottom MLP -> top_in[:, 0:128]
    hipLaunchKernelGGL(bottom_mlp_kernel, dim3(BATCH / 8), dim3(256), 0, stream,
                       dense, W0, b0, W1, b1, W2, b2, top_in);

    // 2) gather + interaction -> top_in[:, 128:506]
    hipLaunchKernelGGL(interact_kernel, dim3(BATCH), dim3(256), 0, stream,
                       cat, table, top_in);

    // 3) top MLP
    // L0: (8192,506) x (506,1024) -> bufX, relu
    hipLaunchKernelGGL(gemm_bias_act_kernel, dim3(BATCH / 64, 1024 / 64), dim3(256), 0, stream,
                       top_in, LDT, T0, 1024, tb0, bufX, 1024, 506, 1);
    // L1: (8192,1024) x (1024,1024) -> bufY, relu
    hipLaunchKernelGGL(gemm_bias_act_kernel, dim3(BATCH / 64, 1024 / 64), dim3(256), 0, stream,
                       bufX, 1024, T1, 1024, tb1, bufY, 1024, 1024, 1);
    // L2: (8192,1024) x (1024,512) -> bufX, relu
    hipLaunchKernelGGL(gemm_bias_act_kernel, dim3(BATCH / 64, 512 / 64), dim3(256), 0, stream,
                       bufY, 1024, T2, 512, tb2, bufX, 512, 1024, 1);
    // L3: (8192,512) x (512,256) -> bufY, relu
    hipLaunchKernelGGL(gemm_bias_act_kernel, dim3(BATCH / 64, 256 / 64), dim3(256), 0, stream,
                       bufX, 512, T3, 256, tb3, bufY, 256, 512, 1);
    // L4: (8192,256) x (256,1) + sigmoid -> out
    hipLaunchKernelGGL(final_layer_kernel, dim3(BATCH / 4), dim3(256), 0, stream,
                       bufY, T4, tb4, out);
}

// Round 3
// 208.901 us; speedup vs baseline: 3.7068x; 3.7068x over previous
//
#include <hip/hip_runtime.h>
#include <hip/hip_bf16.h>
#include <math.h>

#define BATCH 8192

typedef __bf16 bf16x8 __attribute__((ext_vector_type(8)));
typedef float f32x4 __attribute__((ext_vector_type(4)));

__device__ __forceinline__ unsigned short f2bf(float f) {
    unsigned int u = __float_as_uint(f);
    u = u + 0x7FFFu + ((u >> 16) & 1u);   // RNE
    return (unsigned short)(u >> 16);
}
__device__ __forceinline__ float bf2f(unsigned short h) {
    return __uint_as_float(((unsigned int)h) << 16);
}
__device__ __forceinline__ void async16(const void* g, void* l) {
    __builtin_amdgcn_global_load_lds(
        (const __attribute__((address_space(1))) unsigned int*)g,
        (__attribute__((address_space(3))) unsigned int*)l, 16, 0, 0);
}

// ---------------------------------------------------------------------------
// Kernel 1: fused bottom MLP  13 -> 512 -> 256 -> 128 (ReLU each).
// 8 rows/block, 256 threads. Writes fp32 bot_out (for interaction) and
// bf16 copy into A0[:, 0:128].
// ---------------------------------------------------------------------------
__global__ __launch_bounds__(256) void bottom_mlp_kernel(
    const float* __restrict__ dense,
    const float* __restrict__ W0, const float* __restrict__ b0,
    const float* __restrict__ W1, const float* __restrict__ b1,
    const float* __restrict__ W2, const float* __restrict__ b2,
    float* __restrict__ botf,            // (B,128) fp32
    unsigned short* __restrict__ A0)     // (B,512) bf16
{
    __shared__ float xs[8][16];
    __shared__ float h1s[8][512];
    __shared__ float h2s[8][260];

    const int t = threadIdx.x;
    const int row0 = blockIdx.x * 8;

    if (t < 8 * 13) {
        int r = t / 13, k = t % 13;
        xs[r][k] = dense[(size_t)(row0 + r) * 13 + k];
    }
    __syncthreads();

    #pragma unroll
    for (int jj = 0; jj < 2; ++jj) {
        const int j = t + jj * 256;
        float acc[8];
        const float bj = b0[j];
        #pragma unroll
        for (int r = 0; r < 8; ++r) acc[r] = bj;
        #pragma unroll
        for (int k = 0; k < 13; ++k) {
            float w = W0[k * 512 + j];
            #pragma unroll
            for (int r = 0; r < 8; ++r) acc[r] += xs[r][k] * w;
        }
        #pragma unroll
        for (int r = 0; r < 8; ++r) h1s[r][j] = fmaxf(acc[r], 0.f);
    }
    __syncthreads();

    {
        const int j = t;
        float acc[8];
        const float bj = b1[j];
        #pragma unroll
        for (int r = 0; r < 8; ++r) acc[r] = bj;
        for (int k = 0; k < 512; k += 4) {
            float w0 = W1[(k + 0) * 256 + j];
            float w1 = W1[(k + 1) * 256 + j];
            float w2 = W1[(k + 2) * 256 + j];
            float w3 = W1[(k + 3) * 256 + j];
            #pragma unroll
            for (int r = 0; r < 8; ++r) {
                float4 h = *reinterpret_cast<const float4*>(&h1s[r][k]);
                acc[r] += h.x * w0 + h.y * w1 + h.z * w2 + h.w * w3;
            }
        }
        #pragma unroll
        for (int r = 0; r < 8; ++r) h2s[r][j] = fmaxf(acc[r], 0.f);
    }
    __syncthreads();

    {
        const int j = t & 127;
        const int r0 = (t >> 7) * 4;
        float acc[4];
        const float bj = b2[j];
        #pragma unroll
        for (int q = 0; q < 4; ++q) acc[q] = bj;
        for (int k = 0; k < 256; k += 4) {
            float w0 = W2[(k + 0) * 128 + j];
            float w1 = W2[(k + 1) * 128 + j];
            float w2 = W2[(k + 2) * 128 + j];
            float w3 = W2[(k + 3) * 128 + j];
            #pragma unroll
            for (int q = 0; q < 4; ++q) {
                float4 h = *reinterpret_cast<const float4*>(&h2s[r0 + q][k]);
                acc[q] += h.x * w0 + h.y * w1 + h.z * w2 + h.w * w3;
            }
        }
        #pragma unroll
        for (int q = 0; q < 4; ++q) {
            float v = fmaxf(acc[q], 0.f);
            botf[(size_t)(row0 + r0 + q) * 128 + j] = v;
            A0[(size_t)(row0 + r0 + q) * 512 + j] = f2bf(v);
        }
    }
}

// ---------------------------------------------------------------------------
// Kernel 2: embedding gather + pairwise interaction (fp32 dots -> bf16).
// ---------------------------------------------------------------------------
__global__ __launch_bounds__(256) void interact_kernel(
    const int* __restrict__ cat,
    const float* __restrict__ table,
    const float* __restrict__ botf,      // (B,128) fp32
    unsigned short* __restrict__ A0)     // (B,512) bf16
{
    __shared__ float fs[27][132];
    __shared__ int idx[26];

    const int t = threadIdx.x;
    const int row = blockIdx.x;

    if (t < 26) idx[t] = cat[(size_t)row * 26 + t] + t * 100000;
    __syncthreads();

    for (int q = t; q < 27 * 32; q += 256) {
        const int i  = q >> 5;
        const int c4 = q & 31;
        const float* src = (i == 0) ? (botf + (size_t)row * 128)
                                    : (table + (size_t)idx[i - 1] * 128);
        float4 v = reinterpret_cast<const float4*>(src)[c4];
        fs[i][c4 * 4 + 0] = v.x;
        fs[i][c4 * 4 + 1] = v.y;
        fs[i][c4 * 4 + 2] = v.z;
        fs[i][c4 * 4 + 3] = v.w;
    }
    __syncthreads();

    for (int p = t; p < 378; p += 256) {
        int i = 0, rem = p;
        while (rem >= 27 - i) { rem -= 27 - i; ++i; }
        const int j = i + rem;
        float s = 0.f;
        for (int k = 0; k < 128; k += 4) {
            float4 a = *reinterpret_cast<const float4*>(&fs[i][k]);
            float4 b = *reinterpret_cast<const float4*>(&fs[j][k]);
            s += a.x * b.x + a.y * b.y + a.z * b.z + a.w * b.w;
        }
        A0[(size_t)row * 512 + 128 + p] = f2bf(s);
    }
    if (t < 6) A0[(size_t)row * 512 + 506 + t] = 0;  // zero K-pad
}

// ---------------------------------------------------------------------------
// Kernel 3: weight transpose+convert  W fp32 (K,N) -> Wt bf16 (N,Kpad),
// zero-filled rows k in [K,Kpad).
// ---------------------------------------------------------------------------
__global__ __launch_bounds__(256) void wt_transpose_kernel(
    const float* __restrict__ W, unsigned short* __restrict__ Wt,
    int K, int N, int Kpad)
{
    __shared__ float tile[32][33];
    const int kb = blockIdx.x * 32, nb = blockIdx.y * 32;
    const int tx = threadIdx.x & 31, ty = threadIdx.x >> 5;  // ty 0..7

    #pragma unroll
    for (int r = 0; r < 32; r += 8) {
        int k = kb + ty + r;
        tile[ty + r][tx] = (k < K) ? W[(size_t)k * N + nb + tx] : 0.f;
    }
    __syncthreads();
    #pragma unroll
    for (int r = 0; r < 32; r += 8) {
        Wt[(size_t)(nb + ty + r) * Kpad + kb + tx] = f2bf(tile[tx][ty + r]);
    }
}

// ---------------------------------------------------------------------------
// Kernel 4: bf16 MFMA GEMM, 128x128 tile, BK=32, 4 waves (2x2), each wave
// 64x64 (4x4 frags of 16x16x32). A:(M,K) bf16, Bt:(N,K) bf16 (pre-transposed
// weights). C = act(A*B + bias) -> bf16 (M,N). fp32 accumulate.
// LDS staged via global_load_lds w=16, XOR-swizzled (chunk ^= (row>>1)&3).
// ---------------------------------------------------------------------------
__global__ __launch_bounds__(256) void gemm_bf16_kernel(
    const unsigned short* __restrict__ A,
    const unsigned short* __restrict__ Bt,
    const float* __restrict__ bias,
    unsigned short* __restrict__ C,
    int K, int N, int relu)
{
    __shared__ unsigned short As[128 * 32];
    __shared__ unsigned short Bs[128 * 32];

    const int t = threadIdx.x;
    const int lane = t & 63;
    const int wid = t >> 6;
    const int wr = wid >> 1, wc = wid & 1;
    const int row0 = blockIdx.x * 128;
    const int col0 = blockIdx.y * 128;

    // staging roles: q in {0,1}; 16B unit index l16 = q*256+t
    int rowS[2], swzS[2];
    const char* gA[2]; const char* gB[2];
    char* lA[2]; char* lB[2];
    #pragma unroll
    for (int q = 0; q < 2; ++q) {
        int l16 = q * 256 + t;
        int row = l16 >> 2, chunk = l16 & 3;
        rowS[q] = row;
        swzS[q] = chunk ^ ((row >> 1) & 3);
        gA[q] = (const char*)A  + ((size_t)(row0 + row) * K + swzS[q] * 8) * 2;
        gB[q] = (const char*)Bt + ((size_t)(col0 + row) * K + swzS[q] * 8) * 2;
        lA[q] = (char*)As + l16 * 16;
        lB[q] = (char*)Bs + l16 * 16;
    }

    // fragment read offsets (bytes into As/Bs), constant over k-loop
    const int kb = lane >> 4;
    const int r15 = lane & 15;
    int aoff[4], boff[4];
    #pragma unroll
    for (int m = 0; m < 4; ++m) {
        int r = wr * 64 + m * 16 + r15;
        aoff[m] = r * 64 + ((kb ^ ((r >> 1) & 3)) << 4);
        int c = wc * 64 + m * 16 + r15;
        boff[m] = c * 64 + ((kb ^ ((c >> 1) & 3)) << 4);
    }

    f32x4 acc[4][4] = {};

    for (int k0 = 0; k0 < K; k0 += 32) {
        #pragma unroll
        for (int q = 0; q < 2; ++q) {
            async16(gA[q] + (size_t)k0 * 2, lA[q]);
            async16(gB[q] + (size_t)k0 * 2, lB[q]);
        }
        __syncthreads();

        bf16x8 af[4], bfr[4];
        #pragma unroll
        for (int m = 0; m < 4; ++m)
            af[m] = *reinterpret_cast<const bf16x8*>((const char*)As + aoff[m]);
        #pragma unroll
        for (int n = 0; n < 4; ++n)
            bfr[n] = *reinterpret_cast<const bf16x8*>((const char*)Bs + boff[n]);

        #pragma unroll
        for (int m = 0; m < 4; ++m)
            #pragma unroll
            for (int n = 0; n < 4; ++n)
                acc[m][n] = __builtin_amdgcn_mfma_f32_16x16x32_bf16(
                    af[m], bfr[n], acc[m][n], 0, 0, 0);
        __syncthreads();
    }

    // epilogue: C row = (lane>>4)*4 + reg, col = lane&15 within each frag
    #pragma unroll
    for (int n = 0; n < 4; ++n) {
        const int col_g = col0 + wc * 64 + n * 16 + r15;
        const float bn = bias[col_g];
        #pragma unroll
        for (int m = 0; m < 4; ++m) {
            const int row_base = row0 + wr * 64 + m * 16 + (lane >> 4) * 4;
            #pragma unroll
            for (int reg = 0; reg < 4; ++reg) {
                float v = acc[m][n][reg] + bn;
                if (relu) v = fmaxf(v, 0.f);
                C[(size_t)(row_base + reg) * N + col_g] = f2bf(v);
            }
        }
    }
}

// ---------------------------------------------------------------------------
// Kernel 5: final layer 256 -> 1 + sigmoid. One wave per row.
// ---------------------------------------------------------------------------
__global__ __launch_bounds__(256) void final_layer_kernel(
    const unsigned short* __restrict__ A,   // (B,256) bf16
    const float* __restrict__ T4,
    const float* __restrict__ tb4,
    float* __restrict__ out)
{
    const int t = threadIdx.x;
    const int lane = t & 63;
    const int wave = t >> 6;
    const int row = blockIdx.x * 4 + wave;

    ushort4 a4 = reinterpret_cast<const ushort4*>(A + (size_t)row * 256)[lane];
    float4 w = reinterpret_cast<const float4*>(T4)[lane];
    float s = bf2f(a4.x) * w.x + bf2f(a4.y) * w.y + bf2f(a4.z) * w.z + bf2f(a4.w) * w.w;
    #pragma unroll
    for (int off = 32; off > 0; off >>= 1) s += __shfl_down(s, off, 64);
    if (lane == 0) out[row] = 1.f / (1.f + expf(-(s + tb4[0])));
}

// ---------------------------------------------------------------------------
extern "C" void kernel_launch(void* const* d_in, const int* in_sizes, int n_in,
                              void* d_out, int out_size, void* d_ws, size_t ws_size,
                              hipStream_t stream)
{
    const float* dense = (const float*)d_in[0];
    const int*   cat   = (const int*)d_in[1];
    const float* table = (const float*)d_in[2];
    const float* W0 = (const float*)d_in[3];
    const float* b0 = (const float*)d_in[4];
    const float* W1 = (const float*)d_in[5];
    const float* b1 = (const float*)d_in[6];
    const float* W2 = (const float*)d_in[7];
    const float* b2 = (const float*)d_in[8];
    const float* T0 = (const float*)d_in[9];
    const float* tb0 = (const float*)d_in[10];
    const float* T1 = (const float*)d_in[11];
    const float* tb1 = (const float*)d_in[12];
    const float* T2 = (const float*)d_in[13];
    const float* tb2 = (const float*)d_in[14];
    const float* T3 = (const float*)d_in[15];
    const float* tb3 = (const float*)d_in[16];
    const float* T4 = (const float*)d_in[17];
    const float* tb4 = (const float*)d_in[18];
    float* out = (float*)d_out;

    // workspace layout (bytes)
    char* ws = (char*)d_ws;
    unsigned short* A0   = (unsigned short*)(ws);                       // 8192x512  bf16  8 MB
    unsigned short* act1 = (unsigned short*)(ws + 8u * 1024 * 1024);    // 8192x1024 bf16 16 MB
    unsigned short* act2 = (unsigned short*)(ws + 24u * 1024 * 1024);   // 8192x1024 bf16 16 MB
    float*          botf = (float*)(ws + 40u * 1024 * 1024);            // 8192x128  fp32  4 MB
    unsigned short* T0t  = (unsigned short*)(ws + 44u * 1024 * 1024);   // 1024x512  bf16  1 MB
    unsigned short* T1t  = (unsigned short*)(ws + 46u * 1024 * 1024);   // 1024x1024 bf16  2 MB
    unsigned short* T2t  = (unsigned short*)(ws + 48u * 1024 * 1024);   // 512x1024  bf16  1 MB
    unsigned short* T3t  = (unsigned short*)(ws + 50u * 1024 * 1024);   // 256x512   bf16  0.25 MB

    // weight conversions (K, N, Kpad)
    hipLaunchKernelGGL(wt_transpose_kernel, dim3(512 / 32, 1024 / 32), dim3(256), 0, stream,
                       T0, T0t, 506, 1024, 512);
    hipLaunchKernelGGL(wt_transpose_kernel, dim3(1024 / 32, 1024 / 32), dim3(256), 0, stream,
                       T1, T1t, 1024, 1024, 1024);
    hipLaunchKernelGGL(wt_transpose_kernel, dim3(1024 / 32, 512 / 32), dim3(256), 0, stream,
                       T2, T2t, 1024, 512, 1024);
    hipLaunchKernelGGL(wt_transpose_kernel, dim3(512 / 32, 256 / 32), dim3(256), 0, stream,
                       T3, T3t, 512, 256, 512);

    // bottom MLP
    hipLaunchKernelGGL(bottom_mlp_kernel, dim3(BATCH / 8), dim3(256), 0, stream,
                       dense, W0, b0, W1, b1, W2, b2, botf, A0);

    // gather + interaction
    hipLaunchKernelGGL(interact_kernel, dim3(BATCH), dim3(256), 0, stream,
                       cat, table, botf, A0);

    // top MLP (bf16 MFMA)
    hipLaunchKernelGGL(gemm_bf16_kernel, dim3(BATCH / 128, 1024 / 128), dim3(256), 0, stream,
                       A0, T0t, tb0, act1, 512, 1024, 1);
    hipLaunchKernelGGL(gemm_bf16_kernel, dim3(BATCH / 128, 1024 / 128), dim3(256), 0, stream,
                       act1, T1t, tb1, act2, 1024, 1024, 1);
    hipLaunchKernelGGL(gemm_bf16_kernel, dim3(BATCH / 128, 512 / 128), dim3(256), 0, stream,
                       act2, T2t, tb2, act1, 1024, 512, 1);
    hipLaunchKernelGGL(gemm_bf16_kernel, dim3(BATCH / 128, 256 / 128), dim3(256), 0, stream,
                       act1, T3t, tb3, act2, 512, 256, 1);

    // final layer
    hipLaunchKernelGGL(final_layer_kernel, dim3(BATCH / 4), dim3(256), 0, stream,
                       act2, T4, tb4, out);
}

// Round 5
// 169.577 us; speedup vs baseline: 4.5664x; 1.2319x over previous
//
#include <hip/hip_runtime.h>
#include <hip/hip_bf16.h>
#include <math.h>

#define BATCH 8192

typedef __bf16 bf16x8 __attribute__((ext_vector_type(8)));
typedef float f32x4 __attribute__((ext_vector_type(4)));

__device__ __forceinline__ unsigned short f2bf(float f) {
    unsigned int u = __float_as_uint(f);
    u = u + 0x7FFFu + ((u >> 16) & 1u);   // RNE
    return (unsigned short)(u >> 16);
}
__device__ __forceinline__ float bf2f(unsigned short h) {
    return __uint_as_float(((unsigned int)h) << 16);
}
__device__ __forceinline__ void async16(const void* g, void* l) {
    __builtin_amdgcn_global_load_lds(
        (const __attribute__((address_space(1))) unsigned int*)g,
        (__attribute__((address_space(3))) unsigned int*)l, 16, 0, 0);
}

// ---------------------------------------------------------------------------
// Kernel 1: bottom layer 1 only: 13 -> 512, fp32 compute, bf16 store.
// 8 rows/block, 256 threads.
// ---------------------------------------------------------------------------
__global__ __launch_bounds__(256) void bottom13_kernel(
    const float* __restrict__ dense,
    const float* __restrict__ W0, const float* __restrict__ b0,
    unsigned short* __restrict__ h1)     // (B,512) bf16
{
    __shared__ float xs[8][16];
    const int t = threadIdx.x;
    const int row0 = blockIdx.x * 8;

    if (t < 8 * 13) {
        int r = t / 13, k = t % 13;
        xs[r][k] = dense[(size_t)(row0 + r) * 13 + k];
    }
    __syncthreads();

    #pragma unroll
    for (int jj = 0; jj < 2; ++jj) {
        const int j = t + jj * 256;
        float acc[8];
        const float bj = b0[j];
        #pragma unroll
        for (int r = 0; r < 8; ++r) acc[r] = bj;
        #pragma unroll
        for (int k = 0; k < 13; ++k) {
            float w = W0[k * 512 + j];
            #pragma unroll
            for (int r = 0; r < 8; ++r) acc[r] += xs[r][k] * w;
        }
        #pragma unroll
        for (int r = 0; r < 8; ++r)
            h1[(size_t)(row0 + r) * 512 + j] = f2bf(fmaxf(acc[r], 0.f));
    }
}

// ---------------------------------------------------------------------------
// Kernel 2: fused weight transpose+convert for all 6 weights in one launch.
// W fp32 (K,N) -> Wt bf16 (N, Kpad), zero-filled rows k in [K, Kpad).
// ---------------------------------------------------------------------------
struct TransDesc { const float* W; unsigned short* Wt; int K, N, nkb, tile0; };
struct TransDescs { TransDesc d[6]; };

__global__ __launch_bounds__(256) void trans_all_kernel(TransDescs td)
{
    __shared__ float tile[32][33];
    const int b = blockIdx.x;
    int i = 0;
    #pragma unroll
    for (int q = 1; q < 6; ++q) if (b >= td.d[q].tile0) i = q;
    const TransDesc D = td.d[i];
    const int tl = b - D.tile0;
    const int kb = (tl % D.nkb) * 32;
    const int nb = (tl / D.nkb) * 32;
    const int Kpad = D.nkb * 32;
    const int tx = threadIdx.x & 31, ty = threadIdx.x >> 5;

    #pragma unroll
    for (int r = 0; r < 32; r += 8) {
        int k = kb + ty + r;
        tile[ty + r][tx] = (k < D.K) ? D.W[(size_t)k * D.N + nb + tx] : 0.f;
    }
    __syncthreads();
    #pragma unroll
    for (int r = 0; r < 32; r += 8) {
        D.Wt[(size_t)(nb + ty + r) * Kpad + kb + tx] = f2bf(tile[tx][ty + r]);
    }
}

// ---------------------------------------------------------------------------
// Kernel 3: embedding gather + pairwise interaction (fp32 dots -> bf16).
// ---------------------------------------------------------------------------
__global__ __launch_bounds__(256) void interact_kernel(
    const int* __restrict__ cat,
    const float* __restrict__ table,
    const float* __restrict__ botf,      // (B,128) fp32
    unsigned short* __restrict__ A0)     // (B,512) bf16
{
    __shared__ float fs[27][132];
    __shared__ int idx[26];

    const int t = threadIdx.x;
    const int row = blockIdx.x;

    if (t < 26) idx[t] = cat[(size_t)row * 26 + t] + t * 100000;
    __syncthreads();

    for (int q = t; q < 27 * 32; q += 256) {
        const int i  = q >> 5;
        const int c4 = q & 31;
        const float* src = (i == 0) ? (botf + (size_t)row * 128)
                                    : (table + (size_t)idx[i - 1] * 128);
        float4 v = reinterpret_cast<const float4*>(src)[c4];
        fs[i][c4 * 4 + 0] = v.x;
        fs[i][c4 * 4 + 1] = v.y;
        fs[i][c4 * 4 + 2] = v.z;
        fs[i][c4 * 4 + 3] = v.w;
    }
    __syncthreads();

    for (int p = t; p < 378; p += 256) {
        int i = 0, rem = p;
        while (rem >= 27 - i) { rem -= 27 - i; ++i; }
        const int j = i + rem;
        float s = 0.f;
        for (int k = 0; k < 128; k += 4) {
            float4 a = *reinterpret_cast<const float4*>(&fs[i][k]);
            float4 b = *reinterpret_cast<const float4*>(&fs[j][k]);
            s += a.x * b.x + a.y * b.y + a.z * b.z + a.w * b.w;
        }
        A0[(size_t)row * 512 + 128 + p] = f2bf(s);
    }
    if (t < 6) A0[(size_t)row * 512 + 506 + t] = 0;  // zero K-pad
}

// ---------------------------------------------------------------------------
// Kernel 4: bf16 MFMA GEMM, 128x128 tile, BK=32, 4 waves (2x2), each wave
// 64x64 (4x4 frags of 16x16x32). A:(M,K) bf16, Bt:(N,Kpad) bf16.
// C = act(A*B + bias) -> bf16 (M,ldc); optional fp32 mirror Cf (M,N).
// LDS staged via global_load_lds w=16, XOR-swizzled source + swizzled read.
// ---------------------------------------------------------------------------
__global__ __launch_bounds__(256) void gemm_bf16_kernel(
    const unsigned short* __restrict__ A,
    const unsigned short* __restrict__ Bt,
    const float* __restrict__ bias,
    unsigned short* __restrict__ C,
    float* __restrict__ Cf,
    int K, int N, int ldc, int relu)
{
    __shared__ unsigned short As[128 * 32];
    __shared__ unsigned short Bs[128 * 32];

    const int t = threadIdx.x;
    const int lane = t & 63;
    const int wid = t >> 6;
    const int wr = wid >> 1, wc = wid & 1;
    const int row0 = blockIdx.x * 128;
    const int col0 = blockIdx.y * 128;

    const char* gA[2]; const char* gB[2];
    char* lA[2]; char* lB[2];
    #pragma unroll
    for (int q = 0; q < 2; ++q) {
        int l16 = q * 256 + t;
        int row = l16 >> 2, chunk = l16 & 3;
        int swz = chunk ^ ((row >> 1) & 3);
        gA[q] = (const char*)A  + ((size_t)(row0 + row) * K + swz * 8) * 2;
        gB[q] = (const char*)Bt + ((size_t)(col0 + row) * K + swz * 8) * 2;
        lA[q] = (char*)As + l16 * 16;
        lB[q] = (char*)Bs + l16 * 16;
    }

    const int kb = lane >> 4;
    const int r15 = lane & 15;
    int aoff[4], boff[4];
    #pragma unroll
    for (int m = 0; m < 4; ++m) {
        int r = wr * 64 + m * 16 + r15;
        aoff[m] = r * 64 + ((kb ^ ((r >> 1) & 3)) << 4);
        int c = wc * 64 + m * 16 + r15;
        boff[m] = c * 64 + ((kb ^ ((c >> 1) & 3)) << 4);
    }

    f32x4 acc[4][4] = {};

    for (int k0 = 0; k0 < K; k0 += 32) {
        #pragma unroll
        for (int q = 0; q < 2; ++q) {
            async16(gA[q] + (size_t)k0 * 2, lA[q]);
            async16(gB[q] + (size_t)k0 * 2, lB[q]);
        }
        __syncthreads();

        bf16x8 af[4], bfr[4];
        #pragma unroll
        for (int m = 0; m < 4; ++m)
            af[m] = *reinterpret_cast<const bf16x8*>((const char*)As + aoff[m]);
        #pragma unroll
        for (int n = 0; n < 4; ++n)
            bfr[n] = *reinterpret_cast<const bf16x8*>((const char*)Bs + boff[n]);

        #pragma unroll
        for (int m = 0; m < 4; ++m)
            #pragma unroll
            for (int n = 0; n < 4; ++n)
                acc[m][n] = __builtin_amdgcn_mfma_f32_16x16x32_bf16(
                    af[m], bfr[n], acc[m][n], 0, 0, 0);
        __syncthreads();
    }

    // epilogue: within frag, C row = (lane>>4)*4 + reg, col = lane&15
    #pragma unroll
    for (int n = 0; n < 4; ++n) {
        const int col_g = col0 + wc * 64 + n * 16 + r15;
        const float bn = bias[col_g];
        #pragma unroll
        for (int m = 0; m < 4; ++m) {
            const int row_base = row0 + wr * 64 + m * 16 + (lane >> 4) * 4;
            #pragma unroll
            for (int reg = 0; reg < 4; ++reg) {
                float v = acc[m][n][reg] + bn;
                if (relu) v = fmaxf(v, 0.f);
                C[(size_t)(row_base + reg) * ldc + col_g] = f2bf(v);
                if (Cf) Cf[(size_t)(row_base + reg) * N + col_g] = v;
            }
        }
    }
}

// ---------------------------------------------------------------------------
// Kernel 5: final layer 256 -> 1 + sigmoid. One wave per row.
// ---------------------------------------------------------------------------
__global__ __launch_bounds__(256) void final_layer_kernel(
    const unsigned short* __restrict__ A,   // (B,256) bf16
    const float* __restrict__ T4,
    const float* __restrict__ tb4,
    float* __restrict__ out)
{
    const int t = threadIdx.x;
    const int lane = t & 63;
    const int wave = t >> 6;
    const int row = blockIdx.x * 4 + wave;

    ushort4 a4 = reinterpret_cast<const ushort4*>(A + (size_t)row * 256)[lane];
    float4 w = reinterpret_cast<const float4*>(T4)[lane];
    float s = bf2f(a4.x) * w.x + bf2f(a4.y) * w.y + bf2f(a4.z) * w.z + bf2f(a4.w) * w.w;
    #pragma unroll
    for (int off = 32; off > 0; off >>= 1) s += __shfl_down(s, off, 64);
    if (lane == 0) out[row] = 1.f / (1.f + expf(-(s + tb4[0])));
}

// ---------------------------------------------------------------------------
extern "C" void kernel_launch(void* const* d_in, const int* in_sizes, int n_in,
                              void* d_out, int out_size, void* d_ws, size_t ws_size,
                              hipStream_t stream)
{
    const float* dense = (const float*)d_in[0];
    const int*   cat   = (const int*)d_in[1];
    const float* table = (const float*)d_in[2];
    const float* W0 = (const float*)d_in[3];
    const float* b0 = (const float*)d_in[4];
    const float* W1 = (const float*)d_in[5];
    const float* b1 = (const float*)d_in[6];
    const float* W2 = (const float*)d_in[7];
    const float* b2 = (const float*)d_in[8];
    const float* T0 = (const float*)d_in[9];
    const float* tb0 = (const float*)d_in[10];
    const float* T1 = (const float*)d_in[11];
    const float* tb1 = (const float*)d_in[12];
    const float* T2 = (const float*)d_in[13];
    const float* tb2 = (const float*)d_in[14];
    const float* T3 = (const float*)d_in[15];
    const float* tb3 = (const float*)d_in[16];
    const float* T4 = (const float*)d_in[17];
    const float* tb4 = (const float*)d_in[18];
    float* out = (float*)d_out;

    // workspace layout (1 MB units)
    char* ws = (char*)d_ws;
    unsigned short* A0   = (unsigned short*)(ws);                          // 8192x512  bf16  8 MB
    unsigned short* act1 = (unsigned short*)(ws + (((size_t)8)  << 20));   // 8192x1024 bf16 16 MB
    unsigned short* act2 = (unsigned short*)(ws + (((size_t)24) << 20));   // 8192x1024 bf16 16 MB
    float*          botf = (float*)(ws + (((size_t)40) << 20));            // 8192x128  fp32  4 MB
    unsigned short* h1   = (unsigned short*)(ws + (((size_t)44) << 20));   // 8192x512  bf16  8 MB
    unsigned short* h2   = (unsigned short*)(ws + (((size_t)52) << 20));   // 8192x256  bf16  4 MB
    unsigned short* W1t  = (unsigned short*)(ws + (((size_t)56) << 20));   // 256x512
    unsigned short* W2t  = (unsigned short*)(ws + (((size_t)57) << 20));   // 128x256
    unsigned short* T0t  = (unsigned short*)(ws + (((size_t)58) << 20));   // 1024x512
    unsigned short* T1t  = (unsigned short*)(ws + (((size_t)60) << 20));   // 1024x1024
    unsigned short* T2t  = (unsigned short*)(ws + (((size_t)63) << 20));   // 512x1024
    unsigned short* T3t  = (unsigned short*)(ws + (((size_t)66) << 20));   // 256x512

    // fused weight transpose: {W, Wt, K, N, nkb(=Kpad/32), tile0}
    TransDescs td;
    td.d[0] = { W1, W1t,  512,  256, 16,    0 };   // 16*8  = 128 tiles
    td.d[1] = { W2, W2t,  256,  128,  8,  128 };   // 8*4   = 32
    td.d[2] = { T0, T0t,  506, 1024, 16,  160 };   // 16*32 = 512
    td.d[3] = { T1, T1t, 1024, 1024, 32,  672 };   // 32*32 = 1024
    td.d[4] = { T2, T2t, 1024,  512, 32, 1696 };   // 32*16 = 512
    td.d[5] = { T3, T3t,  512,  256, 16, 2208 };   // 16*8  = 128
    const int total_tiles = 2336;
    hipLaunchKernelGGL(trans_all_kernel, dim3(total_tiles), dim3(256), 0, stream, td);

    // bottom layer 1 (fp32 VALU) -> h1 bf16
    hipLaunchKernelGGL(bottom13_kernel, dim3(BATCH / 8), dim3(256), 0, stream,
                       dense, W0, b0, h1);

    // bottom layer 2: (B,512)@(512,256) -> h2, relu
    hipLaunchKernelGGL(gemm_bf16_kernel, dim3(BATCH / 128, 256 / 128), dim3(256), 0, stream,
                       h1, W1t, b1, h2, (float*)nullptr, 512, 256, 256, 1);

    // bottom layer 3: (B,256)@(256,128) -> A0[:,0:128] (ldc=512) + botf fp32
    hipLaunchKernelGGL(gemm_bf16_kernel, dim3(BATCH / 128, 1), dim3(256), 0, stream,
                       h2, W2t, b2, A0, botf, 256, 128, 512, 1);

    // gather + interaction -> A0[:,128:506], zero pad
    hipLaunchKernelGGL(interact_kernel, dim3(BATCH), dim3(256), 0, stream,
                       cat, table, botf, A0);

    // top MLP (bf16 MFMA)
    hipLaunchKernelGGL(gemm_bf16_kernel, dim3(BATCH / 128, 1024 / 128), dim3(256), 0, stream,
                       A0, T0t, tb0, act1, (float*)nullptr, 512, 1024, 1024, 1);
    hipLaunchKernelGGL(gemm_bf16_kernel, dim3(BATCH / 128, 1024 / 128), dim3(256), 0, stream,
                       act1, T1t, tb1, act2, (float*)nullptr, 1024, 1024, 1024, 1);
    hipLaunchKernelGGL(gemm_bf16_kernel, dim3(BATCH / 128, 512 / 128), dim3(256), 0, stream,
                       act2, T2t, tb2, act1, (float*)nullptr, 1024, 512, 512, 1);
    hipLaunchKernelGGL(gemm_bf16_kernel, dim3(BATCH / 128, 256 / 128), dim3(256), 0, stream,
                       act1, T3t, tb3, act2, (float*)nullptr, 512, 256, 256, 1);

    // final layer
    hipLaunchKernelGGL(final_layer_kernel, dim3(BATCH / 4), dim3(256), 0, stream,
                       act2, T4, tb4, out);
}

// Round 6
// 153.682 us; speedup vs baseline: 5.0387x; 1.1034x over previous
//
#include <hip/hip_runtime.h>
#include <hip/hip_bf16.h>
#include <math.h>

#define BATCH 8192

typedef __bf16 bf16x8 __attribute__((ext_vector_type(8)));
typedef float f32x4 __attribute__((ext_vector_type(4)));

__device__ __forceinline__ unsigned short f2bf(float f) {
    unsigned int u = __float_as_uint(f);
    u = u + 0x7FFFu + ((u >> 16) & 1u);   // RNE
    return (unsigned short)(u >> 16);
}
__device__ __forceinline__ float bf2f(unsigned short h) {
    return __uint_as_float(((unsigned int)h) << 16);
}
__device__ __forceinline__ void async16(const void* g, void* l) {
    __builtin_amdgcn_global_load_lds(
        (const __attribute__((address_space(1))) unsigned int*)g,
        (__attribute__((address_space(3))) unsigned int*)l, 16, 0, 0);
}

// ---------------------------------------------------------------------------
// Kernel 1: bottom layer 1 only: 13 -> 512, fp32 compute, bf16 store.
// ---------------------------------------------------------------------------
__global__ __launch_bounds__(256) void bottom13_kernel(
    const float* __restrict__ dense,
    const float* __restrict__ W0, const float* __restrict__ b0,
    unsigned short* __restrict__ h1)     // (B,512) bf16
{
    __shared__ float xs[8][16];
    const int t = threadIdx.x;
    const int row0 = blockIdx.x * 8;

    if (t < 8 * 13) {
        int r = t / 13, k = t % 13;
        xs[r][k] = dense[(size_t)(row0 + r) * 13 + k];
    }
    __syncthreads();

    #pragma unroll
    for (int jj = 0; jj < 2; ++jj) {
        const int j = t + jj * 256;
        float acc[8];
        const float bj = b0[j];
        #pragma unroll
        for (int r = 0; r < 8; ++r) acc[r] = bj;
        #pragma unroll
        for (int k = 0; k < 13; ++k) {
            float w = W0[k * 512 + j];
            #pragma unroll
            for (int r = 0; r < 8; ++r) acc[r] += xs[r][k] * w;
        }
        #pragma unroll
        for (int r = 0; r < 8; ++r)
            h1[(size_t)(row0 + r) * 512 + j] = f2bf(fmaxf(acc[r], 0.f));
    }
}

// ---------------------------------------------------------------------------
// Kernel 2: fused weight transpose+convert for all 6 weights in one launch.
// ---------------------------------------------------------------------------
struct TransDesc { const float* W; unsigned short* Wt; int K, N, nkb, tile0; };
struct TransDescs { TransDesc d[6]; };

__global__ __launch_bounds__(256) void trans_all_kernel(TransDescs td)
{
    __shared__ float tile[32][33];
    const int b = blockIdx.x;
    int i = 0;
    #pragma unroll
    for (int q = 1; q < 6; ++q) if (b >= td.d[q].tile0) i = q;
    const TransDesc D = td.d[i];
    const int tl = b - D.tile0;
    const int kb = (tl % D.nkb) * 32;
    const int nb = (tl / D.nkb) * 32;
    const int Kpad = D.nkb * 32;
    const int tx = threadIdx.x & 31, ty = threadIdx.x >> 5;

    #pragma unroll
    for (int r = 0; r < 32; r += 8) {
        int k = kb + ty + r;
        tile[ty + r][tx] = (k < D.K) ? D.W[(size_t)k * D.N + nb + tx] : 0.f;
    }
    __syncthreads();
    #pragma unroll
    for (int r = 0; r < 32; r += 8) {
        D.Wt[(size_t)(nb + ty + r) * Kpad + kb + tx] = f2bf(tile[tx][ty + r]);
    }
}

// ---------------------------------------------------------------------------
// Kernel 3: embedding gather + pairwise interaction (fp32 dots -> bf16).
// ---------------------------------------------------------------------------
__global__ __launch_bounds__(256) void interact_kernel(
    const int* __restrict__ cat,
    const float* __restrict__ table,
    const float* __restrict__ botf,      // (B,128) fp32
    unsigned short* __restrict__ A0)     // (B,512) bf16
{
    __shared__ float fs[27][132];
    __shared__ int idx[26];

    const int t = threadIdx.x;
    const int row = blockIdx.x;

    if (t < 26) idx[t] = cat[(size_t)row * 26 + t] + t * 100000;
    __syncthreads();

    for (int q = t; q < 27 * 32; q += 256) {
        const int i  = q >> 5;
        const int c4 = q & 31;
        const float* src = (i == 0) ? (botf + (size_t)row * 128)
                                    : (table + (size_t)idx[i - 1] * 128);
        float4 v = reinterpret_cast<const float4*>(src)[c4];
        fs[i][c4 * 4 + 0] = v.x;
        fs[i][c4 * 4 + 1] = v.y;
        fs[i][c4 * 4 + 2] = v.z;
        fs[i][c4 * 4 + 3] = v.w;
    }
    __syncthreads();

    for (int p = t; p < 378; p += 256) {
        int i = 0, rem = p;
        while (rem >= 27 - i) { rem -= 27 - i; ++i; }
        const int j = i + rem;
        float s = 0.f;
        for (int k = 0; k < 128; k += 4) {
            float4 a = *reinterpret_cast<const float4*>(&fs[i][k]);
            float4 b = *reinterpret_cast<const float4*>(&fs[j][k]);
            s += a.x * b.x + a.y * b.y + a.z * b.z + a.w * b.w;
        }
        A0[(size_t)row * 512 + 128 + p] = f2bf(s);
    }
    if (t < 6) A0[(size_t)row * 512 + 506 + t] = 0;  // zero K-pad
}

// ---------------------------------------------------------------------------
// Kernel 4: bf16 MFMA GEMM, 128x128 tile, BK=64, 4 waves (2x2), each wave
// 64x64 (4x4 frags of 16x16x32, 2 k-sub-steps). A:(M,K) bf16, Bt:(N,Kpad).
// C = act(A*B + bias) -> bf16 (M,ldc); optional fp32 mirror Cf (M,N).
// LDS via global_load_lds w=16; XOR-swizzle chunk^=(row&7), 8 chunks/row,
// pre-swizzled global source + swizzled ds_read (rule #21). K % 64 == 0.
// ---------------------------------------------------------------------------
__global__ __launch_bounds__(256) void gemm_bf16_kernel(
    const unsigned short* __restrict__ A,
    const unsigned short* __restrict__ Bt,
    const float* __restrict__ bias,
    unsigned short* __restrict__ C,
    float* __restrict__ Cf,
    int K, int N, int ldc, int relu)
{
    __shared__ unsigned short As[128 * 64];
    __shared__ unsigned short Bs[128 * 64];

    const int t = threadIdx.x;
    const int lane = t & 63;
    const int wid = t >> 6;
    const int wr = wid >> 1, wc = wid & 1;
    const int row0 = blockIdx.x * 128;
    const int col0 = blockIdx.y * 128;

    // staging roles: q in {0..3}; 16B unit index l16 = q*256+t, 8 chunks/row
    const char* gA[4]; const char* gB[4];
    char* lA[4]; char* lB[4];
    #pragma unroll
    for (int q = 0; q < 4; ++q) {
        int l16 = q * 256 + t;
        int row = l16 >> 3, chunk = l16 & 7;
        int swz = chunk ^ (row & 7);
        gA[q] = (const char*)A  + ((size_t)(row0 + row) * K + swz * 8) * 2;
        gB[q] = (const char*)Bt + ((size_t)(col0 + row) * K + swz * 8) * 2;
        lA[q] = (char*)As + l16 * 16;
        lB[q] = (char*)Bs + l16 * 16;
    }

    // fragment read offsets (bytes), row stride 128 B, phys chunk = c^(r&7)
    const int kb = lane >> 4;
    const int r15 = lane & 15;
    int aoff[4][2], boff[4][2];
    #pragma unroll
    for (int m = 0; m < 4; ++m) {
        int r = wr * 64 + m * 16 + r15;
        int c = wc * 64 + m * 16 + r15;
        #pragma unroll
        for (int ks = 0; ks < 2; ++ks) {
            aoff[m][ks] = r * 128 + (((ks * 4 + kb) ^ (r & 7)) << 4);
            boff[m][ks] = c * 128 + (((ks * 4 + kb) ^ (c & 7)) << 4);
        }
    }

    f32x4 acc[4][4] = {};

    for (int k0 = 0; k0 < K; k0 += 64) {
        #pragma unroll
        for (int q = 0; q < 4; ++q) {
            async16(gA[q] + (size_t)k0 * 2, lA[q]);
            async16(gB[q] + (size_t)k0 * 2, lB[q]);
        }
        __syncthreads();

        #pragma unroll
        for (int ks = 0; ks < 2; ++ks) {
            bf16x8 af[4], bfr[4];
            #pragma unroll
            for (int m = 0; m < 4; ++m)
                af[m] = *reinterpret_cast<const bf16x8*>((const char*)As + aoff[m][ks]);
            #pragma unroll
            for (int n = 0; n < 4; ++n)
                bfr[n] = *reinterpret_cast<const bf16x8*>((const char*)Bs + boff[n][ks]);

            #pragma unroll
            for (int m = 0; m < 4; ++m)
                #pragma unroll
                for (int n = 0; n < 4; ++n)
                    acc[m][n] = __builtin_amdgcn_mfma_f32_16x16x32_bf16(
                        af[m], bfr[n], acc[m][n], 0, 0, 0);
        }
        __syncthreads();
    }

    // epilogue: within frag, C row = (lane>>4)*4 + reg, col = lane&15
    #pragma unroll
    for (int n = 0; n < 4; ++n) {
        const int col_g = col0 + wc * 64 + n * 16 + r15;
        const float bn = bias[col_g];
        #pragma unroll
        for (int m = 0; m < 4; ++m) {
            const int row_base = row0 + wr * 64 + m * 16 + (lane >> 4) * 4;
            #pragma unroll
            for (int reg = 0; reg < 4; ++reg) {
                float v = acc[m][n][reg] + bn;
                if (relu) v = fmaxf(v, 0.f);
                C[(size_t)(row_base + reg) * ldc + col_g] = f2bf(v);
                if (Cf) Cf[(size_t)(row_base + reg) * N + col_g] = v;
            }
        }
    }
}

// ---------------------------------------------------------------------------
// Kernel 5: final layer 256 -> 1 + sigmoid. One wave per row.
// ---------------------------------------------------------------------------
__global__ __launch_bounds__(256) void final_layer_kernel(
    const unsigned short* __restrict__ A,   // (B,256) bf16
    const float* __restrict__ T4,
    const float* __restrict__ tb4,
    float* __restrict__ out)
{
    const int t = threadIdx.x;
    const int lane = t & 63;
    const int wave = t >> 6;
    const int row = blockIdx.x * 4 + wave;

    ushort4 a4 = reinterpret_cast<const ushort4*>(A + (size_t)row * 256)[lane];
    float4 w = reinterpret_cast<const float4*>(T4)[lane];
    float s = bf2f(a4.x) * w.x + bf2f(a4.y) * w.y + bf2f(a4.z) * w.z + bf2f(a4.w) * w.w;
    #pragma unroll
    for (int off = 32; off > 0; off >>= 1) s += __shfl_down(s, off, 64);
    if (lane == 0) out[row] = 1.f / (1.f + expf(-(s + tb4[0])));
}

// ---------------------------------------------------------------------------
extern "C" void kernel_launch(void* const* d_in, const int* in_sizes, int n_in,
                              void* d_out, int out_size, void* d_ws, size_t ws_size,
                              hipStream_t stream)
{
    const float* dense = (const float*)d_in[0];
    const int*   cat   = (const int*)d_in[1];
    const float* table = (const float*)d_in[2];
    const float* W0 = (const float*)d_in[3];
    const float* b0 = (const float*)d_in[4];
    const float* W1 = (const float*)d_in[5];
    const float* b1 = (const float*)d_in[6];
    const float* W2 = (const float*)d_in[7];
    const float* b2 = (const float*)d_in[8];
    const float* T0 = (const float*)d_in[9];
    const float* tb0 = (const float*)d_in[10];
    const float* T1 = (const float*)d_in[11];
    const float* tb1 = (const float*)d_in[12];
    const float* T2 = (const float*)d_in[13];
    const float* tb2 = (const float*)d_in[14];
    const float* T3 = (const float*)d_in[15];
    const float* tb3 = (const float*)d_in[16];
    const float* T4 = (const float*)d_in[17];
    const float* tb4 = (const float*)d_in[18];
    float* out = (float*)d_out;

    // workspace layout (1 MB units)
    char* ws = (char*)d_ws;
    unsigned short* A0   = (unsigned short*)(ws);                          // 8192x512  bf16  8 MB
    unsigned short* act1 = (unsigned short*)(ws + (((size_t)8)  << 20));   // 8192x1024 bf16 16 MB
    unsigned short* act2 = (unsigned short*)(ws + (((size_t)24) << 20));   // 8192x1024 bf16 16 MB
    float*          botf = (float*)(ws + (((size_t)40) << 20));            // 8192x128  fp32  4 MB
    unsigned short* h1   = (unsigned short*)(ws + (((size_t)44) << 20));   // 8192x512  bf16  8 MB
    unsigned short* h2   = (unsigned short*)(ws + (((size_t)52) << 20));   // 8192x256  bf16  4 MB
    unsigned short* W1t  = (unsigned short*)(ws + (((size_t)56) << 20));   // 256x512
    unsigned short* W2t  = (unsigned short*)(ws + (((size_t)57) << 20));   // 128x256
    unsigned short* T0t  = (unsigned short*)(ws + (((size_t)58) << 20));   // 1024x512
    unsigned short* T1t  = (unsigned short*)(ws + (((size_t)60) << 20));   // 1024x1024
    unsigned short* T2t  = (unsigned short*)(ws + (((size_t)63) << 20));   // 512x1024
    unsigned short* T3t  = (unsigned short*)(ws + (((size_t)66) << 20));   // 256x512

    // fused weight transpose: {W, Wt, K, N, nkb(=Kpad/32), tile0}
    TransDescs td;
    td.d[0] = { W1, W1t,  512,  256, 16,    0 };   // 16*8  = 128 tiles
    td.d[1] = { W2, W2t,  256,  128,  8,  128 };   // 8*4   = 32
    td.d[2] = { T0, T0t,  506, 1024, 16,  160 };   // 16*32 = 512
    td.d[3] = { T1, T1t, 1024, 1024, 32,  672 };   // 32*32 = 1024
    td.d[4] = { T2, T2t, 1024,  512, 32, 1696 };   // 32*16 = 512
    td.d[5] = { T3, T3t,  512,  256, 16, 2208 };   // 16*8  = 128
    const int total_tiles = 2336;
    hipLaunchKernelGGL(trans_all_kernel, dim3(total_tiles), dim3(256), 0, stream, td);

    // bottom layer 1 (fp32 VALU) -> h1 bf16
    hipLaunchKernelGGL(bottom13_kernel, dim3(BATCH / 8), dim3(256), 0, stream,
                       dense, W0, b0, h1);

    // bottom layer 2: (B,512)@(512,256) -> h2, relu
    hipLaunchKernelGGL(gemm_bf16_kernel, dim3(BATCH / 128, 256 / 128), dim3(256), 0, stream,
                       h1, W1t, b1, h2, (float*)nullptr, 512, 256, 256, 1);

    // bottom layer 3: (B,256)@(256,128) -> A0[:,0:128] (ldc=512) + botf fp32
    hipLaunchKernelGGL(gemm_bf16_kernel, dim3(BATCH / 128, 1), dim3(256), 0, stream,
                       h2, W2t, b2, A0, botf, 256, 128, 512, 1);

    // gather + interaction -> A0[:,128:506], zero pad
    hipLaunchKernelGGL(interact_kernel, dim3(BATCH), dim3(256), 0, stream,
                       cat, table, botf, A0);

    // top MLP (bf16 MFMA)
    hipLaunchKernelGGL(gemm_bf16_kernel, dim3(BATCH / 128, 1024 / 128), dim3(256), 0, stream,
                       A0, T0t, tb0, act1, (float*)nullptr, 512, 1024, 1024, 1);
    hipLaunchKernelGGL(gemm_bf16_kernel, dim3(BATCH / 128, 1024 / 128), dim3(256), 0, stream,
                       act1, T1t, tb1, act2, (float*)nullptr, 1024, 1024, 1024, 1);
    hipLaunchKernelGGL(gemm_bf16_kernel, dim3(BATCH / 128, 512 / 128), dim3(256), 0, stream,
                       act2, T2t, tb2, act1, (float*)nullptr, 1024, 512, 512, 1);
    hipLaunchKernelGGL(gemm_bf16_kernel, dim3(BATCH / 128, 256 / 128), dim3(256), 0, stream,
                       act1, T3t, tb3, act2, (float*)nullptr, 512, 256, 256, 1);

    // final layer
    hipLaunchKernelGGL(final_layer_kernel, dim3(BATCH / 4), dim3(256), 0, stream,
                       act2, T4, tb4, out);
}

// Round 8
// 149.174 us; speedup vs baseline: 5.1910x; 1.0302x over previous
//
#include <hip/hip_runtime.h>
#include <hip/hip_bf16.h>
#include <math.h>

#define BATCH 8192

typedef __bf16 bf16x8 __attribute__((ext_vector_type(8)));
typedef float f32x4 __attribute__((ext_vector_type(4)));

__device__ __forceinline__ unsigned short f2bf(float f) {
    unsigned int u = __float_as_uint(f);
    u = u + 0x7FFFu + ((u >> 16) & 1u);   // RNE
    return (unsigned short)(u >> 16);
}
__device__ __forceinline__ float bf2f(unsigned short h) {
    return __uint_as_float(((unsigned int)h) << 16);
}
__device__ __forceinline__ void async16(const void* g, void* l) {
    __builtin_amdgcn_global_load_lds(
        (const __attribute__((address_space(1))) unsigned int*)g,
        (__attribute__((address_space(3))) unsigned int*)l, 16, 0, 0);
}

// ---------------------------------------------------------------------------
// Kernel 1: bottom layer 1 only: 13 -> 512, fp32 compute, bf16 store.
// ---------------------------------------------------------------------------
__global__ __launch_bounds__(256) void bottom13_kernel(
    const float* __restrict__ dense,
    const float* __restrict__ W0, const float* __restrict__ b0,
    unsigned short* __restrict__ h1)     // (B,512) bf16
{
    __shared__ float xs[8][16];
    const int t = threadIdx.x;
    const int row0 = blockIdx.x * 8;

    if (t < 8 * 13) {
        int r = t / 13, k = t % 13;
        xs[r][k] = dense[(size_t)(row0 + r) * 13 + k];
    }
    __syncthreads();

    #pragma unroll
    for (int jj = 0; jj < 2; ++jj) {
        const int j = t + jj * 256;
        float acc[8];
        const float bj = b0[j];
        #pragma unroll
        for (int r = 0; r < 8; ++r) acc[r] = bj;
        #pragma unroll
        for (int k = 0; k < 13; ++k) {
            float w = W0[k * 512 + j];
            #pragma unroll
            for (int r = 0; r < 8; ++r) acc[r] += xs[r][k] * w;
        }
        #pragma unroll
        for (int r = 0; r < 8; ++r)
            h1[(size_t)(row0 + r) * 512 + j] = f2bf(fmaxf(acc[r], 0.f));
    }
}

// ---------------------------------------------------------------------------
// Kernel 2: fused weight transpose+convert for all 6 weights in one launch.
// ---------------------------------------------------------------------------
struct TransDesc { const float* W; unsigned short* Wt; int K, N, nkb, tile0; };
struct TransDescs { TransDesc d[6]; };

__global__ __launch_bounds__(256) void trans_all_kernel(TransDescs td)
{
    __shared__ float tile[32][33];
    const int b = blockIdx.x;
    int i = 0;
    #pragma unroll
    for (int q = 1; q < 6; ++q) if (b >= td.d[q].tile0) i = q;
    const TransDesc D = td.d[i];
    const int tl = b - D.tile0;
    const int kb = (tl % D.nkb) * 32;
    const int nb = (tl / D.nkb) * 32;
    const int Kpad = D.nkb * 32;
    const int tx = threadIdx.x & 31, ty = threadIdx.x >> 5;

    #pragma unroll
    for (int r = 0; r < 32; r += 8) {
        int k = kb + ty + r;
        tile[ty + r][tx] = (k < D.K) ? D.W[(size_t)k * D.N + nb + tx] : 0.f;
    }
    __syncthreads();
    #pragma unroll
    for (int r = 0; r < 32; r += 8) {
        D.Wt[(size_t)(nb + ty + r) * Kpad + kb + tx] = f2bf(tile[tx][ty + r]);
    }
}

// ---------------------------------------------------------------------------
// Kernel 3: embedding gather + pairwise interaction (fp32 dots -> bf16).
// ---------------------------------------------------------------------------
__global__ __launch_bounds__(256) void interact_kernel(
    const int* __restrict__ cat,
    const float* __restrict__ table,
    const float* __restrict__ botf,      // (B,128) fp32
    unsigned short* __restrict__ A0)     // (B,512) bf16
{
    __shared__ float fs[27][132];
    __shared__ int idx[26];

    const int t = threadIdx.x;
    const int row = blockIdx.x;

    if (t < 26) idx[t] = cat[(size_t)row * 26 + t] + t * 100000;
    __syncthreads();

    for (int q = t; q < 27 * 32; q += 256) {
        const int i  = q >> 5;
        const int c4 = q & 31;
        const float* src = (i == 0) ? (botf + (size_t)row * 128)
                                    : (table + (size_t)idx[i - 1] * 128);
        float4 v = reinterpret_cast<const float4*>(src)[c4];
        fs[i][c4 * 4 + 0] = v.x;
        fs[i][c4 * 4 + 1] = v.y;
        fs[i][c4 * 4 + 2] = v.z;
        fs[i][c4 * 4 + 3] = v.w;
    }
    __syncthreads();

    for (int p = t; p < 378; p += 256) {
        int i = 0, rem = p;
        while (rem >= 27 - i) { rem -= 27 - i; ++i; }
        const int j = i + rem;
        float s = 0.f;
        for (int k = 0; k < 128; k += 4) {
            float4 a = *reinterpret_cast<const float4*>(&fs[i][k]);
            float4 b = *reinterpret_cast<const float4*>(&fs[j][k]);
            s += a.x * b.x + a.y * b.y + a.z * b.z + a.w * b.w;
        }
        A0[(size_t)row * 512 + 128 + p] = f2bf(s);
    }
    if (t < 6) A0[(size_t)row * 512 + 506 + t] = 0;  // zero K-pad
}

// ---------------------------------------------------------------------------
// Kernel 4: bf16 MFMA GEMM, 128x128 tile, BK=64, DOUBLE-BUFFERED 2-phase
// pipeline (stage t+1 || compute t, ONE barrier per K-tile). 4 waves (2x2),
// each wave 64x64 (4x4 frags of 16x16x32, 2 k-sub-steps).
// A:(M,K) bf16, Bt:(N,Kpad) bf16. C = act(A*B+bias) -> bf16 (M,ldc);
// optional fp32 mirror Cf (M,N).
// LDS via global_load_lds w=16; XOR-swizzle chunk^=(row&7), pre-swizzled
// global source + swizzled ds_read (rule #21). K % 64 == 0.
// ---------------------------------------------------------------------------
__global__ __launch_bounds__(256) void gemm_bf16_kernel(
    const unsigned short* __restrict__ A,
    const unsigned short* __restrict__ Bt,
    const float* __restrict__ bias,
    unsigned short* __restrict__ C,
    float* __restrict__ Cf,
    int K, int N, int ldc, int relu)
{
    __shared__ unsigned short As[2][128 * 64];
    __shared__ unsigned short Bs[2][128 * 64];

    const int t = threadIdx.x;
    const int lane = t & 63;
    const int wid = t >> 6;
    const int wr = wid >> 1, wc = wid & 1;
    const int row0 = blockIdx.x * 128;
    const int col0 = blockIdx.y * 128;

    // staging roles: q in {0..3}; 16B unit index l16 = q*256+t, 8 chunks/row
    const char* gA[4]; const char* gB[4];
    int ldst[4];
    #pragma unroll
    for (int q = 0; q < 4; ++q) {
        int l16 = q * 256 + t;
        int row = l16 >> 3, chunk = l16 & 7;
        int swz = chunk ^ (row & 7);
        gA[q] = (const char*)A  + ((size_t)(row0 + row) * K + swz * 8) * 2;
        gB[q] = (const char*)Bt + ((size_t)(col0 + row) * K + swz * 8) * 2;
        ldst[q] = l16 * 16;
    }

    // fragment read offsets (bytes), row stride 128 B, phys chunk = c^(r&7)
    const int kb = lane >> 4;
    const int r15 = lane & 15;
    int aoff[4][2], boff[4][2];
    #pragma unroll
    for (int m = 0; m < 4; ++m) {
        int r = wr * 64 + m * 16 + r15;
        int c = wc * 64 + m * 16 + r15;
        #pragma unroll
        for (int ks = 0; ks < 2; ++ks) {
            aoff[m][ks] = r * 128 + (((ks * 4 + kb) ^ (r & 7)) << 4);
            boff[m][ks] = c * 128 + (((ks * 4 + kb) ^ (c & 7)) << 4);
        }
    }

    f32x4 acc[4][4] = {};

    const int nt = K >> 6;

    // prologue: stage tile 0 into buf 0
    #pragma unroll
    for (int q = 0; q < 4; ++q) {
        async16(gA[q], (char*)As[0] + ldst[q]);
        async16(gB[q], (char*)Bs[0] + ldst[q]);
    }
    __syncthreads();

    int cur = 0;
    for (int tt = 0; tt < nt; ++tt) {
        // issue next-tile stage into buf cur^1 (loads fly under the MFMAs)
        if (tt + 1 < nt) {
            const size_t koff = (size_t)(tt + 1) * 64 * 2;
            #pragma unroll
            for (int q = 0; q < 4; ++q) {
                async16(gA[q] + koff, (char*)As[cur ^ 1] + ldst[q]);
                async16(gB[q] + koff, (char*)Bs[cur ^ 1] + ldst[q]);
            }
        }

        const char* aB = (const char*)As[cur];
        const char* bB = (const char*)Bs[cur];
        #pragma unroll
        for (int ks = 0; ks < 2; ++ks) {
            bf16x8 af[4], bfr[4];
            #pragma unroll
            for (int m = 0; m < 4; ++m)
                af[m] = *reinterpret_cast<const bf16x8*>(aB + aoff[m][ks]);
            #pragma unroll
            for (int n = 0; n < 4; ++n)
                bfr[n] = *reinterpret_cast<const bf16x8*>(bB + boff[n][ks]);

            #pragma unroll
            for (int m = 0; m < 4; ++m)
                #pragma unroll
                for (int n = 0; n < 4; ++n)
                    acc[m][n] = __builtin_amdgcn_mfma_f32_16x16x32_bf16(
                        af[m], bfr[n], acc[m][n], 0, 0, 0);
        }
        // single barrier: drains vmcnt (next tile staged) + lgkm (our reads)
        __syncthreads();
        cur ^= 1;
    }

    // epilogue: within frag, C row = (lane>>4)*4 + reg, col = lane&15
    #pragma unroll
    for (int n = 0; n < 4; ++n) {
        const int col_g = col0 + wc * 64 + n * 16 + r15;
        const float bn = bias[col_g];
        #pragma unroll
        for (int m = 0; m < 4; ++m) {
            const int row_base = row0 + wr * 64 + m * 16 + (lane >> 4) * 4;
            #pragma unroll
            for (int reg = 0; reg < 4; ++reg) {
                float v = acc[m][n][reg] + bn;
                if (relu) v = fmaxf(v, 0.f);
                C[(size_t)(row_base + reg) * ldc + col_g] = f2bf(v);
                if (Cf) Cf[(size_t)(row_base + reg) * N + col_g] = v;
            }
        }
    }
}

// ---------------------------------------------------------------------------
// Kernel 5: final layer 256 -> 1 + sigmoid. One wave per row.
// ---------------------------------------------------------------------------
__global__ __launch_bounds__(256) void final_layer_kernel(
    const unsigned short* __restrict__ A,   // (B,256) bf16
    const float* __restrict__ T4,
    const float* __restrict__ tb4,
    float* __restrict__ out)
{
    const int t = threadIdx.x;
    const int lane = t & 63;
    const int wave = t >> 6;
    const int row = blockIdx.x * 4 + wave;

    ushort4 a4 = reinterpret_cast<const ushort4*>(A + (size_t)row * 256)[lane];
    float4 w = reinterpret_cast<const float4*>(T4)[lane];
    float s = bf2f(a4.x) * w.x + bf2f(a4.y) * w.y + bf2f(a4.z) * w.z + bf2f(a4.w) * w.w;
    #pragma unroll
    for (int off = 32; off > 0; off >>= 1) s += __shfl_down(s, off, 64);
    if (lane == 0) out[row] = 1.f / (1.f + expf(-(s + tb4[0])));
}

// ---------------------------------------------------------------------------
extern "C" void kernel_launch(void* const* d_in, const int* in_sizes, int n_in,
                              void* d_out, int out_size, void* d_ws, size_t ws_size,
                              hipStream_t stream)
{
    const float* dense = (const float*)d_in[0];
    const int*   cat   = (const int*)d_in[1];
    const float* table = (const float*)d_in[2];
    const float* W0 = (const float*)d_in[3];
    const float* b0 = (const float*)d_in[4];
    const float* W1 = (const float*)d_in[5];
    const float* b1 = (const float*)d_in[6];
    const float* W2 = (const float*)d_in[7];
    const float* b2 = (const float*)d_in[8];
    const float* T0 = (const float*)d_in[9];
    const float* tb0 = (const float*)d_in[10];
    const float* T1 = (const float*)d_in[11];
    const float* tb1 = (const float*)d_in[12];
    const float* T2 = (const float*)d_in[13];
    const float* tb2 = (const float*)d_in[14];
    const float* T3 = (const float*)d_in[15];
    const float* tb3 = (const float*)d_in[16];
    const float* T4 = (const float*)d_in[17];
    const float* tb4 = (const float*)d_in[18];
    float* out = (float*)d_out;

    // workspace layout (1 MB units)
    char* ws = (char*)d_ws;
    unsigned short* A0   = (unsigned short*)(ws);                          // 8192x512  bf16  8 MB
    unsigned short* act1 = (unsigned short*)(ws + (((size_t)8)  << 20));   // 8192x1024 bf16 16 MB
    unsigned short* act2 = (unsigned short*)(ws + (((size_t)24) << 20));   // 8192x1024 bf16 16 MB
    float*          botf = (float*)(ws + (((size_t)40) << 20));            // 8192x128  fp32  4 MB
    unsigned short* h1   = (unsigned short*)(ws + (((size_t)44) << 20));   // 8192x512  bf16  8 MB
    unsigned short* h2   = (unsigned short*)(ws + (((size_t)52) << 20));   // 8192x256  bf16  4 MB
    unsigned short* W1t  = (unsigned short*)(ws + (((size_t)56) << 20));   // 256x512
    unsigned short* W2t  = (unsigned short*)(ws + (((size_t)57) << 20));   // 128x256
    unsigned short* T0t  = (unsigned short*)(ws + (((size_t)58) << 20));   // 1024x512
    unsigned short* T1t  = (unsigned short*)(ws + (((size_t)60) << 20));   // 1024x1024
    unsigned short* T2t  = (unsigned short*)(ws + (((size_t)63) << 20));   // 512x1024
    unsigned short* T3t  = (unsigned short*)(ws + (((size_t)66) << 20));   // 256x512

    // fused weight transpose: {W, Wt, K, N, nkb(=Kpad/32), tile0}
    TransDescs td;
    td.d[0] = { W1, W1t,  512,  256, 16,    0 };   // 16*8  = 128 tiles
    td.d[1] = { W2, W2t,  256,  128,  8,  128 };   // 8*4   = 32
    td.d[2] = { T0, T0t,  506, 1024, 16,  160 };   // 16*32 = 512
    td.d[3] = { T1, T1t, 1024, 1024, 32,  672 };   // 32*32 = 1024
    td.d[4] = { T2, T2t, 1024,  512, 32, 1696 };   // 32*16 = 512
    td.d[5] = { T3, T3t,  512,  256, 16, 2208 };   // 16*8  = 128
    const int total_tiles = 2336;
    hipLaunchKernelGGL(trans_all_kernel, dim3(total_tiles), dim3(256), 0, stream, td);

    // bottom layer 1 (fp32 VALU) -> h1 bf16
    hipLaunchKernelGGL(bottom13_kernel, dim3(BATCH / 8), dim3(256), 0, stream,
                       dense, W0, b0, h1);

    // bottom layer 2: (B,512)@(512,256) -> h2, relu
    hipLaunchKernelGGL(gemm_bf16_kernel, dim3(BATCH / 128, 256 / 128), dim3(256), 0, stream,
                       h1, W1t, b1, h2, (float*)nullptr, 512, 256, 256, 1);

    // bottom layer 3: (B,256)@(256,128) -> A0[:,0:128] (ldc=512) + botf fp32
    hipLaunchKernelGGL(gemm_bf16_kernel, dim3(BATCH / 128, 1), dim3(256), 0, stream,
                       h2, W2t, b2, A0, botf, 256, 128, 512, 1);

    // gather + interaction -> A0[:,128:506], zero pad
    hipLaunchKernelGGL(interact_kernel, dim3(BATCH), dim3(256), 0, stream,
                       cat, table, botf, A0);

    // top MLP (bf16 MFMA)
    hipLaunchKernelGGL(gemm_bf16_kernel, dim3(BATCH / 128, 1024 / 128), dim3(256), 0, stream,
                       A0, T0t, tb0, act1, (float*)nullptr, 512, 1024, 1024, 1);
    hipLaunchKernelGGL(gemm_bf16_kernel, dim3(BATCH / 128, 1024 / 128), dim3(256), 0, stream,
                       act1, T1t, tb1, act2, (float*)nullptr, 1024, 1024, 1024, 1);
    hipLaunchKernelGGL(gemm_bf16_kernel, dim3(BATCH / 128, 512 / 128), dim3(256), 0, stream,
                       act2, T2t, tb2, act1, (float*)nullptr, 1024, 512, 512, 1);
    hipLaunchKernelGGL(gemm_bf16_kernel, dim3(BATCH / 128, 256 / 128), dim3(256), 0, stream,
                       act1, T3t, tb3, act2, (float*)nullptr, 512, 256, 256, 1);

    // final layer
    hipLaunchKernelGGL(final_layer_kernel, dim3(BATCH / 4), dim3(256), 0, stream,
                       act2, T4, tb4, out);
}